// Round 1
// baseline (183.482 us; speedup 1.0000x reference)
//
#include <hip/hip_runtime.h>
#include <math.h>

#define TN 8192
#define AN 128
#define NW20 (TN - 20)   // 8172
#define NW10 (TN - 10)   // 8182

// ---- k_main grid ranges ----
#define NB_GRAM 128
#define NB_ROW  512      // 16 rows/block
#define NB_R20  511      // 16 windows/block (4 waves x strip of 4)
#define NB_R10  512
#define NB_WORK (NB_GRAM + NB_ROW + NB_R20 + NB_R10)   // 1663

// ---- workspace double-layout ----
#define WS_STD0 0
#define WS_STDL 1
#define WS_FLAG 7                    // int arrival counter in wsd[7]
#define WS_SPEC 8                    // 64*3 {sum, sumabs, trace}
#define WS_BLK  200                  // NB_WORK*2 per-block scalar slots
#define WS_DEND 4096

// rolling off-diag corr via C.sum() = sum_t (sum_i z_ti)^2; butterfly with
// lane-compression; 4 consecutive windows per wave from one register strip.
// Math verified in R4 (absmax 7.45e-9). Lane owns columns {2*lane, 2*lane+1}
// (column permutation is neutral: all reductions are symmetric over columns).
template <int W>
__device__ __forceinline__ void roll_strip4(const float* __restrict__ x,
                                            int s0, int nwin, int lane,
                                            double& accA, double& accB) {
  constexpr int NR = W + 3;
  float a0[NR], a1[NR];
#pragma unroll
  for (int t = 0; t < NR; ++t) {
    int r = s0 + t; r = (r < TN) ? r : (TN - 1);
    float2 v = *(const float2*)(x + (size_t)r * AN + 2 * lane);
    a0[t] = v.x; a1[t] = v.y;
  }
#pragma unroll
  for (int w4 = 0; w4 < 4; ++w4) {
    int s = s0 + w4;
    if (s < nwin) {
      float sf0 = 0.f, sf1 = 0.f;
#pragma unroll
      for (int t = 0; t < W; ++t) { sf0 += a0[w4 + t]; sf1 += a1[w4 + t]; }
      float mu0 = sf0 / W, mu1 = sf1 / W;
      float v0 = 0.f, v1 = 0.f;
#pragma unroll
      for (int t = 0; t < W; ++t) {
        float d0 = a0[w4 + t] - mu0, d1 = a1[w4 + t] - mu1;
        v0 += d0 * d0; v1 += d1 * d1;
      }
      float i0 = 1.0f / sqrtf(v0), i1 = 1.0f / sqrtf(v1);
      float q[W];
#pragma unroll
      for (int t = 0; t < W; ++t)
        q[t] = (a0[w4 + t] - mu0) * i0 + (a1[w4 + t] - mu1) * i1;
      int n = W;
#pragma unroll
      for (int o = 1; o <= 32; o <<= 1) {
#pragma unroll
        for (int k = 0; k < n; ++k) q[k] += __shfl_xor(q[k], o);
        if (n > 1) {
          int nh = n >> 1;
          bool hi = (lane & o) != 0;
#pragma unroll
          for (int k = 0; k < nh; ++k) q[k] = hi ? q[2 * k + 1] : q[2 * k];
          if (n & 1) { q[nh] = q[2 * nh]; n = nh + 1; } else { n = nh; }
        }
      }
      float alpha = (W == 20) ? ((lane & 16) ? 0.125f : 0.5f)
                              : ((lane & 8) ? 0.0625f : 0.25f);
      float r = q[0] * q[0] * alpha;
#pragma unroll
      for (int o = 32; o; o >>= 1) r += __shfl_xor(r, o);
      if (lane == 0) {
        double off = ((double)r - (double)AN) / ((double)AN * (AN - 1));
        if (W == 20) {
          accA += (off > 0.7) ? 1.0 : 0.0;
        } else {
          accA += off;
          if (s >= TN - W - 5) accB += off;
        }
      }
    }
  }
}

// ============ phase A: all data-parallel work, deterministic slots =======
__global__ void __launch_bounds__(256) k_main(const float* __restrict__ x,
                                              double* __restrict__ wsd,
                                              float* __restrict__ pc,
                                              float* __restrict__ pdg,
                                              float* __restrict__ pg) {
  __shared__ union {
    float stage[8][AN];
    double tacc[4][2];
  } sm;
  const int b = blockIdx.x;
  const int tid = threadIdx.x;
  const int lane = tid & 63;
  const int w = tid >> 6;

  if (b == 0 && tid == 0) *(int*)(wsd + WS_FLAG) = 0;  // arm k_tail sync

  if (b < NB_GRAM) {
    // ---- gram slice: 64 rows, 8x8 register tiles (R1-R5 verified) ----
    int i0 = (tid >> 4) * 8;
    int j0 = (tid & 15) * 8;
    int lrow = tid >> 5;
    int lcol = (tid & 31) * 4;
    const float* xs = x + (size_t)b * 64 * AN;
    float acc[8][8];
#pragma unroll
    for (int a = 0; a < 8; ++a)
#pragma unroll
      for (int c = 0; c < 8; ++c) acc[a][c] = 0.f;
    float4 v = *(const float4*)(xs + lrow * AN + lcol);
    for (int it = 0; it < 8; ++it) {
      __syncthreads();
      *(float4*)(&sm.stage[lrow][lcol]) = v;
      __syncthreads();
      if (it + 1 < 8)
        v = *(const float4*)(xs + ((it + 1) * 8 + lrow) * AN + lcol);
#pragma unroll
      for (int r = 0; r < 8; ++r) {
        float aa[8], bb[8];
        *(float4*)(aa) = *(const float4*)(&sm.stage[r][i0]);
        *(float4*)(aa + 4) = *(const float4*)(&sm.stage[r][i0 + 4]);
        *(float4*)(bb) = *(const float4*)(&sm.stage[r][j0]);
        *(float4*)(bb + 4) = *(const float4*)(&sm.stage[r][j0 + 4]);
#pragma unroll
        for (int ai = 0; ai < 8; ++ai)
#pragma unroll
          for (int bj = 0; bj < 8; ++bj)
            acc[ai][bj] = fmaf(aa[ai], bb[bj], acc[ai][bj]);
      }
    }
    float* dst = pg + (size_t)b * (AN * AN);
#pragma unroll
    for (int ai = 0; ai < 8; ++ai)
#pragma unroll
      for (int bj = 0; bj < 8; bj += 4)
        *(float4*)(dst + (i0 + ai) * AN + j0 + bj) =
            make_float4(acc[ai][bj], acc[ai][bj + 1], acc[ai][bj + 2],
                        acc[ai][bj + 3]);
    if ((tid >> 4) == (tid & 15)) {
#pragma unroll
      for (int k = 0; k < 8; ++k) pdg[b * AN + i0 + k] = acc[k][k];
    }
    if (tid < AN) {
      float cs = 0.f;
      for (int r = 0; r < 64; ++r) cs += xs[r * AN + tid];
      pc[b * AN + tid] = cs;
    }
    return;
  }

  if (b < NB_GRAM + NB_ROW) {
    // ---- per-row std + sign counts, 16 rows/block, float2 cols ----
    int rb = b - NB_GRAM;
    double sstd = 0.0, sconc = 0.0;
    for (int rr = 0; rr < 4; ++rr) {
      int t = rb * 16 + w * 4 + rr;
      float2 xv = *(const float2*)(x + (size_t)t * AN + 2 * lane);
      float x0 = xv.x, x1 = xv.y;
      float s = x0 + x1;
#pragma unroll
      for (int o = 32; o; o >>= 1) s += __shfl_xor(s, o);
      float mean = s * (1.0f / AN);
      float d0 = x0 - mean, d1 = x1 - mean;
      float q = d0 * d0 + d1 * d1;
#pragma unroll
      for (int o = 32; o; o >>= 1) q += __shfl_xor(q, o);
      float sd = sqrtf(q / (float)(AN - 1));
      int pk = (int)(x0 < 0.f) + (int)(x1 < 0.f)
             + (((int)(x0 == 0.f) + (int)(x1 == 0.f)) << 10)
             + (((int)(x0 > 0.f) + (int)(x1 > 0.f)) << 20);
#pragma unroll
      for (int o = 32; o; o >>= 1) pk += __shfl_xor(pk, o);
      if (lane == 0) {
        int nn = pk & 1023, nz = (pk >> 10) & 1023, np = (pk >> 20) & 1023;
        sconc += (double)nn * nn + (double)nz * nz + (double)np * np;
        sstd += (double)sd;
        if (t == 0) wsd[WS_STD0] = (double)sd;
        if (t == TN - 1) wsd[WS_STDL] = (double)sd;
      }
    }
    if (lane == 0) { sm.tacc[w][0] = sstd; sm.tacc[w][1] = sconc; }
    __syncthreads();
    if (tid == 0) {
      wsd[WS_BLK + (size_t)b * 2 + 0] =
          sm.tacc[0][0] + sm.tacc[1][0] + sm.tacc[2][0] + sm.tacc[3][0];
      wsd[WS_BLK + (size_t)b * 2 + 1] =
          sm.tacc[0][1] + sm.tacc[1][1] + sm.tacc[2][1] + sm.tacc[3][1];
    }
    return;
  }

  if (b < NB_GRAM + NB_ROW + NB_R20) {
    int s0 = (b - (NB_GRAM + NB_ROW)) * 16 + w * 4;
    double cnt = 0.0, dummy = 0.0;
    roll_strip4<20>(x, s0, NW20, lane, cnt, dummy);
    if (lane == 0) { sm.tacc[w][0] = cnt; }
    __syncthreads();
    if (tid == 0)
      wsd[WS_BLK + (size_t)b * 2 + 0] =
          sm.tacc[0][0] + sm.tacc[1][0] + sm.tacc[2][0] + sm.tacc[3][0];
    return;
  }

  {
    int s0 = (b - (NB_GRAM + NB_ROW + NB_R20)) * 16 + w * 4;
    double s10 = 0.0, s10l5 = 0.0;
    roll_strip4<10>(x, s0, NW10, lane, s10, s10l5);
    if (lane == 0) { sm.tacc[w][0] = s10; sm.tacc[w][1] = s10l5; }
    __syncthreads();
    if (tid == 0) {
      wsd[WS_BLK + (size_t)b * 2 + 0] =
          sm.tacc[0][0] + sm.tacc[1][0] + sm.tacc[2][0] + sm.tacc[3][0];
      wsd[WS_BLK + (size_t)b * 2 + 1] =
          sm.tacc[0][1] + sm.tacc[1][1] + sm.tacc[2][1] + sm.tacc[3][1];
    }
  }
}

// ====== phase B+C merged: fold -> corr (blocks 0..63) in parallel with
// scalar folds + MLP + pos scan (block 64); block 64 then acquires the
// fold results and runs power iteration + assembly. Only block 64 waits,
// and it waits only on non-waiting blocks -> no deadlock possible. =======
__global__ void __launch_bounds__(256) k_tail(
    const float* __restrict__ x, const float* __restrict__ pos,
    const float* __restrict__ w1, const float* __restrict__ b1,
    const float* __restrict__ gamma, const float* __restrict__ beta,
    const float* __restrict__ w2, const float* __restrict__ b2,
    const float* __restrict__ w3, const float* __restrict__ b3,
    const float* __restrict__ pc, const float* __restrict__ pdg,
    const float* __restrict__ pg, double* __restrict__ wsd,
    float* __restrict__ corr, float* __restrict__ out) {
  __shared__ double r0[256], r1[256], r2[256], r3[256], r4[256];
  int b = blockIdx.x;
  int t = threadIdx.x;
  int lane = t & 63;
  int w = t >> 6;
  int* flg = (int*)(wsd + WS_FLAG);

  if (b < 64) {
    // ---- corr fold (identical math to previous k_fold b<64) ----
    __shared__ double muS[AN], dS[AN];
    if (t < AN) {
      double cs = 0.0, dg = 0.0;
      for (int s = 0; s < NB_GRAM; ++s) {
        cs += (double)pc[s * AN + t];
        dg += (double)pdg[s * AN + t];
      }
      double mu = cs / (double)TN;
      muS[t] = mu;
      dS[t] = sqrt(dg - (double)TN * mu * mu);
    }
    __syncthreads();
    int e = b * 256 + t;
    int i = e >> 7, j = e & (AN - 1);
    double cv = 0.0;
    for (int s = 0; s < NB_GRAM; ++s) cv += (double)pg[(size_t)s * (AN * AN) + e];
    cv -= (double)TN * muS[i] * muS[j];
    double c = cv / (dS[i] * dS[j]);
    corr[e] = (float)c;
    r0[t] = c;
    r1[t] = fabs(c);
    r2[t] = (i == j) ? c : 0.0;
    __syncthreads();
    for (int sft = 128; sft; sft >>= 1) {
      if (t < sft) { r0[t] += r0[t + sft]; r1[t] += r1[t + sft]; r2[t] += r2[t + sft]; }
      __syncthreads();
    }
    if (t == 0) {
      wsd[WS_SPEC + b * 3 + 0] = r0[0];
      wsd[WS_SPEC + b * 3 + 1] = r1[0];
      wsd[WS_SPEC + b * 3 + 2] = r2[0];
    }
    // all threads' global stores are vmcnt-drained by this barrier;
    // t0's agent-scope release then flushes them past the XCD L2.
    __syncthreads();
    if (t == 0)
      __hip_atomic_fetch_add(flg, 1, __ATOMIC_RELEASE, __HIP_MEMORY_SCOPE_AGENT);
    return;
  }

  // =================== block 64: independent work first ===================
  __shared__ float f[2 * AN], prt[256], h1[AN], h2[64], lg[3];
  __shared__ float vv[AN], un[AN], red[4];
  __shared__ double spec[3], scv[8], pr2[4];

  // ---- scalar folds (previous k_fold else-branch), results stay in LDS ----
  {
    double a = 0.0, bc = 0.0, cnt = 0.0, s10 = 0.0, s10l5 = 0.0;
    for (int k = NB_GRAM + t; k < NB_WORK; k += 256) {
      const double* p = wsd + WS_BLK + (size_t)k * 2;
      if (k < NB_GRAM + NB_ROW) { a += p[0]; bc += p[1]; }
      else if (k < NB_GRAM + NB_ROW + NB_R20) cnt += p[0];
      else { s10 += p[0]; s10l5 += p[1]; }
    }
    r0[t] = a; r1[t] = bc; r2[t] = cnt; r3[t] = s10; r4[t] = s10l5;
    __syncthreads();
    for (int sft = 128; sft; sft >>= 1) {
      if (t < sft) {
        r0[t] += r0[t + sft]; r1[t] += r1[t + sft]; r2[t] += r2[t + sft];
        r3[t] += r3[t + sft]; r4[t] += r4[t + sft];
      }
      __syncthreads();
    }
    if (t == 0) {
      scv[0] = r0[0];   // sumstd
      scv[1] = r1[0];   // conc
      scv[2] = r2[0];   // cnt20
      scv[3] = r3[0];   // sum10
      scv[4] = r4[0];   // sum10l5
    }
  }

  // ---- MLP (independent of corr) ----
  f[t] = (t < AN) ? x[(size_t)(TN - 1) * AN + t] : pos[t - AN];
  __syncthreads();
  {
    int n = t & 127, h = t >> 7;
    float acc = 0.f;
    const float* wcol = w1 + h * 128 * AN + n;
    const float* fv = f + h * 128;
    for (int k = 0; k < 128; ++k) acc = fmaf(fv[k], wcol[k * AN], acc);
    prt[t] = acc;
  }
  __syncthreads();
  if (t < AN) {
    float acc = b1[t] + prt[t] + prt[t + 128];
    acc = fmaxf(acc, 0.0f);
    h1[t] = gamma[t] * (acc / sqrtf(1.0f + 1e-5f)) + beta[t];
  }
  __syncthreads();
  if (t < 64) {
    float acc = b2[t];
    for (int k = 0; k < AN; ++k) acc = fmaf(h1[k], w2[k * 64 + t], acc);
    h2[t] = fmaxf(acc, 0.0f);
  }
  __syncthreads();
  if (t < 3) {
    float acc = b3[t];
    for (int k = 0; k < 64; ++k) acc = fmaf(h2[k], w3[k * 3 + t], acc);
    lg[t] = acc;
  }

  // ---- pos |.| sum/max, wave-parallel ----
  if (t < AN) {
    double pa = fabs((double)pos[t]);
    double ps = pa, pm = pa;
#pragma unroll
    for (int o = 32; o; o >>= 1) {
      ps += __shfl_xor(ps, o);
      pm = fmax(pm, __shfl_xor(pm, o));
    }
    if (lane == 0) { pr2[w] = ps; pr2[2 + w] = pm; }
  }
  __syncthreads();
  if (t == 0) {
    float m = fmaxf(lg[0], fmaxf(lg[1], lg[2]));
    float e0 = expf(lg[0] - m), e1 = expf(lg[1] - m), e2 = expf(lg[2] - m);
    scv[5] = (double)(e2 / (e0 + e1 + e2));        // herding_severity
    scv[6] = pr2[0] + pr2[1];                      // pasum
    scv[7] = fmax(pr2[2], pr2[3]);                 // pamax
  }

  // ---- wait for the 64 fold blocks; relaxed poll, single acquire ----
  if (t == 0) {
    while (__hip_atomic_load(flg, __ATOMIC_RELAXED, __HIP_MEMORY_SCOPE_AGENT) < 64)
      __builtin_amdgcn_s_sleep(2);
    (void)__hip_atomic_load(flg, __ATOMIC_ACQUIRE, __HIP_MEMORY_SCOPE_AGENT);
  }
  __syncthreads();

  // ---- fold spec partials ----
  if (t < 64) {
    double s0 = wsd[WS_SPEC + t * 3 + 0];
    double s1 = wsd[WS_SPEC + t * 3 + 1];
    double s2 = wsd[WS_SPEC + t * 3 + 2];
#pragma unroll
    for (int o = 32; o; o >>= 1) {
      s0 += __shfl_xor(s0, o);
      s1 += __shfl_xor(s1, o);
      s2 += __shfl_xor(s2, o);
    }
    if (t == 0) { spec[0] = s0; spec[1] = s1; spec[2] = s2; }
  }
  if (t < AN) vv[t] = 1.0f;
  __syncthreads();

  // ---- power iteration, 12 iters; transposed (symmetric) coalesced reads:
  // thread computes output col c from rows hh*64..hh*64+63; lanes read
  // consecutive addresses -> 256B/instr fully useful, corr L2-hot after it 0.
  int c = t & (AN - 1), hh = t >> 7;
  const float* cp = corr + (size_t)hh * 64 * AN + c;
  float lam = 0.0f;
  for (int it = 0; it < 12; ++it) {
    float acc = 0.f;
#pragma unroll
    for (int k = 0; k < 64; ++k)
      acc = fmaf(cp[(size_t)k * AN], vv[hh * 64 + k], acc);
    prt[t] = acc;
    __syncthreads();
    if (t < AN) {
      float u = prt[t] + prt[t + 128];
      un[t] = u;
      float sq = u * u;
#pragma unroll
      for (int o = 32; o; o >>= 1) sq += __shfl_xor(sq, o);
      if (lane == 0) red[w] = sq;
    }
    __syncthreads();
    lam = sqrtf(red[0] + red[1]);
    if (t < AN) vv[t] = un[t] / lam;
    __syncthreads();
  }

  // ---- final assembly ----
  if (t != 0) return;
  double sev = scv[5];
  double sumstd = scv[0], conc = scv[1], cnt20 = scv[2];
  double sum10 = scv[3], sum10l5 = scv[4];
  double avg_disp = sumstd / (double)TN;
  double trend = -(wsd[WS_STDL] - wsd[WS_STD0]) / (double)(TN - 1);
  double hi = trend / (avg_disp + 1e-6) + 0.5;
  hi = fmin(1.0, fmax(0.0, hi));
  double avg_corr = (spec[0] - spec[2]) / ((double)AN * (AN - 1));
  double sync_ind = (double)lam / (double)AN;
  double sync_risk = fmin(1.0, sync_ind * avg_corr);
  double pl = cnt20 / (double)(TN - 20);
  double rd = 1.0 - spec[1] / ((double)AN * AN);
  double pd = 1.0 - scv[7] / scv[6];
  double dl = 1.0 - sqrt(rd * pd);
  double recent = sum10l5 / 5.0;
  double hist = (sum10 - sum10l5) / (double)(TN - 10 - 5);
  double sraw = (recent - hist) / hist;
  sraw = fmin(1.0, fmax(0.0, sraw));
  double surge = (hist > 0.0) ? sraw : 0.0;
  double ac = (conc / (double)TN - (double)AN) / ((double)AN * (AN - 1));
  double pcup = fmin(1.0, fmax(0.0, (ac - 0.5) * 2.0));
  double cr = (hi + sync_risk + dl) / 3.0;
  out[0] = (float)hi;
  out[1] = (float)sev;
  out[2] = (float)sync_risk;
  out[3] = (float)pl;
  out[4] = (float)dl;
  out[5] = (float)surge;
  out[6] = (float)pcup;
  out[7] = (float)cr;
}

extern "C" void kernel_launch(void* const* d_in, const int* in_sizes, int n_in,
                              void* d_out, int out_size, void* d_ws, size_t ws_size,
                              hipStream_t stream) {
  const float* x     = (const float*)d_in[0];
  const float* pos   = (const float*)d_in[1];
  const float* w1    = (const float*)d_in[2];
  const float* b1    = (const float*)d_in[3];
  const float* gamma = (const float*)d_in[4];
  const float* beta  = (const float*)d_in[5];
  const float* w2    = (const float*)d_in[6];
  const float* b2    = (const float*)d_in[7];
  const float* w3    = (const float*)d_in[8];
  const float* b3    = (const float*)d_in[9];
  float* out = (float*)d_out;
  double* wsd = (double*)d_ws;
  float* corr = (float*)(wsd + WS_DEND);               // [16384]
  float* pc   = corr + AN * AN;                        // [128*128]
  float* pdg  = pc + NB_GRAM * AN;                     // [128*128]
  float* pg   = pdg + NB_GRAM * AN;                    // [128*16384]

  k_main<<<NB_WORK, 256, 0, stream>>>(x, wsd, pc, pdg, pg);
  k_tail<<<65, 256, 0, stream>>>(x, pos, w1, b1, gamma, beta, w2, b2,
                                 w3, b3, pc, pdg, pg, wsd, corr, out);
}

// Round 3
// 127.032 us; speedup vs baseline: 1.4444x; 1.4444x over previous
//
#include <hip/hip_runtime.h>
#include <math.h>

#define TN 8192
#define AN 128
#define NW20 (TN - 20)   // 8172
#define NW10 (TN - 10)   // 8182

// ---- k_main grid ranges ----
#define NB_GRAM 64       // 128 rows/slice (R2: halves fold latency chain)
#define NB_ROW  512      // 16 rows/block
#define NB_R20  511      // 16 windows/block (4 waves x strip of 4)
#define NB_R10  512
#define NB_WORK (NB_GRAM + NB_ROW + NB_R20 + NB_R10)   // 1599

// ---- workspace double-layout ----
#define WS_STD0 0
#define WS_STDL 1
// wsd[2..6]: sumstd, conc, cnt20, sum10, sum10l5   (written by k_fold b==64)
#define WS_SEV  7                    // herding_severity (k_fold b==64)
#define WS_SPEC 8                    // 64*3 {sum, sumabs, trace}
#define WS_BLK  200                  // NB_WORK*2 per-block scalar slots (to 3398)
#define WS_PAS  3400                 // sum |pos|
#define WS_PAM  3401                 // max |pos|
#define WS_DEND 4096

// rolling off-diag corr via C.sum() = sum_t (sum_i z_ti)^2; butterfly with
// lane-compression; 4 consecutive windows per wave from one register strip.
// Math verified earlier (absmax 7.45e-9). Lane owns columns {2*lane, 2*lane+1}
// (column permutation is neutral: all reductions are symmetric over columns).
template <int W>
__device__ __forceinline__ void roll_strip4(const float* __restrict__ x,
                                            int s0, int nwin, int lane,
                                            double& accA, double& accB) {
  constexpr int NR = W + 3;
  float a0[NR], a1[NR];
#pragma unroll
  for (int t = 0; t < NR; ++t) {
    int r = s0 + t; r = (r < TN) ? r : (TN - 1);
    float2 v = *(const float2*)(x + (size_t)r * AN + 2 * lane);
    a0[t] = v.x; a1[t] = v.y;
  }
#pragma unroll
  for (int w4 = 0; w4 < 4; ++w4) {
    int s = s0 + w4;
    if (s < nwin) {
      float sf0 = 0.f, sf1 = 0.f;
#pragma unroll
      for (int t = 0; t < W; ++t) { sf0 += a0[w4 + t]; sf1 += a1[w4 + t]; }
      float mu0 = sf0 / W, mu1 = sf1 / W;
      float v0 = 0.f, v1 = 0.f;
#pragma unroll
      for (int t = 0; t < W; ++t) {
        float d0 = a0[w4 + t] - mu0, d1 = a1[w4 + t] - mu1;
        v0 += d0 * d0; v1 += d1 * d1;
      }
      float i0 = 1.0f / sqrtf(v0), i1 = 1.0f / sqrtf(v1);
      float q[W];
#pragma unroll
      for (int t = 0; t < W; ++t)
        q[t] = (a0[w4 + t] - mu0) * i0 + (a1[w4 + t] - mu1) * i1;
      int n = W;
#pragma unroll
      for (int o = 1; o <= 32; o <<= 1) {
#pragma unroll
        for (int k = 0; k < n; ++k) q[k] += __shfl_xor(q[k], o);
        if (n > 1) {
          int nh = n >> 1;
          bool hi = (lane & o) != 0;
#pragma unroll
          for (int k = 0; k < nh; ++k) q[k] = hi ? q[2 * k + 1] : q[2 * k];
          if (n & 1) { q[nh] = q[2 * nh]; n = nh + 1; } else { n = nh; }
        }
      }
      float alpha = (W == 20) ? ((lane & 16) ? 0.125f : 0.5f)
                              : ((lane & 8) ? 0.0625f : 0.25f);
      float r = q[0] * q[0] * alpha;
#pragma unroll
      for (int o = 32; o; o >>= 1) r += __shfl_xor(r, o);
      if (lane == 0) {
        double off = ((double)r - (double)AN) / ((double)AN * (AN - 1));
        if (W == 20) {
          accA += (off > 0.7) ? 1.0 : 0.0;
        } else {
          accA += off;
          if (s >= TN - W - 5) accB += off;
        }
      }
    }
  }
}

// ============ phase A: all data-parallel work, deterministic slots =======
__global__ void __launch_bounds__(256) k_main(const float* __restrict__ x,
                                              double* __restrict__ wsd,
                                              float* __restrict__ pc,
                                              float* __restrict__ pdg,
                                              float* __restrict__ pg) {
  __shared__ union {
    float stage[8][AN];
    double tacc[4][2];
  } sm;
  const int b = blockIdx.x;
  const int tid = threadIdx.x;
  const int lane = tid & 63;
  const int w = tid >> 6;

  if (b < NB_GRAM) {
    // ---- gram slice: 128 rows, 8x8 register tiles ----
    int i0 = (tid >> 4) * 8;
    int j0 = (tid & 15) * 8;
    int lrow = tid >> 5;
    int lcol = (tid & 31) * 4;
    const float* xs = x + (size_t)b * 128 * AN;
    float acc[8][8];
#pragma unroll
    for (int a = 0; a < 8; ++a)
#pragma unroll
      for (int c = 0; c < 8; ++c) acc[a][c] = 0.f;
    float4 v = *(const float4*)(xs + lrow * AN + lcol);
    for (int it = 0; it < 16; ++it) {
      __syncthreads();
      *(float4*)(&sm.stage[lrow][lcol]) = v;
      __syncthreads();
      if (it + 1 < 16)
        v = *(const float4*)(xs + ((it + 1) * 8 + lrow) * AN + lcol);
#pragma unroll
      for (int r = 0; r < 8; ++r) {
        float aa[8], bb[8];
        *(float4*)(aa) = *(const float4*)(&sm.stage[r][i0]);
        *(float4*)(aa + 4) = *(const float4*)(&sm.stage[r][i0 + 4]);
        *(float4*)(bb) = *(const float4*)(&sm.stage[r][j0]);
        *(float4*)(bb + 4) = *(const float4*)(&sm.stage[r][j0 + 4]);
#pragma unroll
        for (int ai = 0; ai < 8; ++ai)
#pragma unroll
          for (int bj = 0; bj < 8; ++bj)
            acc[ai][bj] = fmaf(aa[ai], bb[bj], acc[ai][bj]);
      }
    }
    float* dst = pg + (size_t)b * (AN * AN);
#pragma unroll
    for (int ai = 0; ai < 8; ++ai)
#pragma unroll
      for (int bj = 0; bj < 8; bj += 4)
        *(float4*)(dst + (i0 + ai) * AN + j0 + bj) =
            make_float4(acc[ai][bj], acc[ai][bj + 1], acc[ai][bj + 2],
                        acc[ai][bj + 3]);
    if ((tid >> 4) == (tid & 15)) {
#pragma unroll
      for (int k = 0; k < 8; ++k) pdg[b * AN + i0 + k] = acc[k][k];
    }
    if (tid < AN) {
      float cs = 0.f;
      for (int r = 0; r < 128; ++r) cs += xs[r * AN + tid];
      pc[b * AN + tid] = cs;
    }
    return;
  }

  if (b < NB_GRAM + NB_ROW) {
    // ---- per-row std + sign counts, 16 rows/block, float2 cols ----
    int rb = b - NB_GRAM;
    double sstd = 0.0, sconc = 0.0;
    for (int rr = 0; rr < 4; ++rr) {
      int t = rb * 16 + w * 4 + rr;
      float2 xv = *(const float2*)(x + (size_t)t * AN + 2 * lane);
      float x0 = xv.x, x1 = xv.y;
      float s = x0 + x1;
#pragma unroll
      for (int o = 32; o; o >>= 1) s += __shfl_xor(s, o);
      float mean = s * (1.0f / AN);
      float d0 = x0 - mean, d1 = x1 - mean;
      float q = d0 * d0 + d1 * d1;
#pragma unroll
      for (int o = 32; o; o >>= 1) q += __shfl_xor(q, o);
      float sd = sqrtf(q / (float)(AN - 1));
      int pk = (int)(x0 < 0.f) + (int)(x1 < 0.f)
             + (((int)(x0 == 0.f) + (int)(x1 == 0.f)) << 10)
             + (((int)(x0 > 0.f) + (int)(x1 > 0.f)) << 20);
#pragma unroll
      for (int o = 32; o; o >>= 1) pk += __shfl_xor(pk, o);
      if (lane == 0) {
        int nn = pk & 1023, nz = (pk >> 10) & 1023, np = (pk >> 20) & 1023;
        sconc += (double)nn * nn + (double)nz * nz + (double)np * np;
        sstd += (double)sd;
        if (t == 0) wsd[WS_STD0] = (double)sd;
        if (t == TN - 1) wsd[WS_STDL] = (double)sd;
      }
    }
    if (lane == 0) { sm.tacc[w][0] = sstd; sm.tacc[w][1] = sconc; }
    __syncthreads();
    if (tid == 0) {
      wsd[WS_BLK + (size_t)b * 2 + 0] =
          sm.tacc[0][0] + sm.tacc[1][0] + sm.tacc[2][0] + sm.tacc[3][0];
      wsd[WS_BLK + (size_t)b * 2 + 1] =
          sm.tacc[0][1] + sm.tacc[1][1] + sm.tacc[2][1] + sm.tacc[3][1];
    }
    return;
  }

  if (b < NB_GRAM + NB_ROW + NB_R20) {
    int s0 = (b - (NB_GRAM + NB_ROW)) * 16 + w * 4;
    double cnt = 0.0, dummy = 0.0;
    roll_strip4<20>(x, s0, NW20, lane, cnt, dummy);
    if (lane == 0) { sm.tacc[w][0] = cnt; }
    __syncthreads();
    if (tid == 0)
      wsd[WS_BLK + (size_t)b * 2 + 0] =
          sm.tacc[0][0] + sm.tacc[1][0] + sm.tacc[2][0] + sm.tacc[3][0];
    return;
  }

  {
    int s0 = (b - (NB_GRAM + NB_ROW + NB_R20)) * 16 + w * 4;
    double s10 = 0.0, s10l5 = 0.0;
    roll_strip4<10>(x, s0, NW10, lane, s10, s10l5);
    if (lane == 0) { sm.tacc[w][0] = s10; sm.tacc[w][1] = s10l5; }
    __syncthreads();
    if (tid == 0) {
      wsd[WS_BLK + (size_t)b * 2 + 0] =
          sm.tacc[0][0] + sm.tacc[1][0] + sm.tacc[2][0] + sm.tacc[3][0];
      wsd[WS_BLK + (size_t)b * 2 + 1] =
          sm.tacc[0][1] + sm.tacc[1][1] + sm.tacc[2][1] + sm.tacc[3][1];
    }
  }
}

// ====== phase B: fold partials -> corr (b<64) + scalar folds/MLP/pos (b==64)
__global__ void __launch_bounds__(256) k_fold(
    const float* __restrict__ pc, const float* __restrict__ pdg,
    const float* __restrict__ pg, double* __restrict__ wsd,
    float* __restrict__ corr, const float* __restrict__ x,
    const float* __restrict__ pos, const float* __restrict__ w1,
    const float* __restrict__ b1, const float* __restrict__ gamma,
    const float* __restrict__ beta, const float* __restrict__ w2,
    const float* __restrict__ b2, const float* __restrict__ w3,
    const float* __restrict__ b3) {
  __shared__ double r0[256], r1[256], r2[256], r3[256], r4[256];
  int b = blockIdx.x;
  int t = threadIdx.x;
  int lane = t & 63;
  int w = t >> 6;
  if (b < 64) {
    __shared__ double muS[AN], dS[AN];
    if (t < AN) {
      double cs = 0.0, dg = 0.0;
#pragma unroll 8
      for (int s = 0; s < NB_GRAM; ++s) {
        cs += (double)pc[s * AN + t];
        dg += (double)pdg[s * AN + t];
      }
      double mu = cs / (double)TN;
      muS[t] = mu;
      dS[t] = sqrt(dg - (double)TN * mu * mu);
    }
    __syncthreads();
    int e = b * 256 + t;
    int i = e >> 7, j = e & (AN - 1);
    double cv = 0.0;
#pragma unroll 16
    for (int s = 0; s < NB_GRAM; ++s) cv += (double)pg[(size_t)s * (AN * AN) + e];
    cv -= (double)TN * muS[i] * muS[j];
    double c = cv / (dS[i] * dS[j]);
    corr[e] = (float)c;
    r0[t] = c;
    r1[t] = fabs(c);
    r2[t] = (i == j) ? c : 0.0;
    __syncthreads();
    for (int sft = 128; sft; sft >>= 1) {
      if (t < sft) { r0[t] += r0[t + sft]; r1[t] += r1[t + sft]; r2[t] += r2[t + sft]; }
      __syncthreads();
    }
    if (t == 0) {
      wsd[WS_SPEC + b * 3 + 0] = r0[0];
      wsd[WS_SPEC + b * 3 + 1] = r1[0];
      wsd[WS_SPEC + b * 3 + 2] = r2[0];
    }
    return;
  }

  // ---- block 64: scalar folds + MLP + pos scan (independent of corr) ----
  __shared__ float f[2 * AN], prt[256], h1[AN], h2[64], lg[3];
  __shared__ double pr2[4];
  {
    double a = 0.0, bc = 0.0, cnt = 0.0, s10 = 0.0, s10l5 = 0.0;
    for (int k = NB_GRAM + t; k < NB_WORK; k += 256) {
      const double* p = wsd + WS_BLK + (size_t)k * 2;
      if (k < NB_GRAM + NB_ROW) { a += p[0]; bc += p[1]; }
      else if (k < NB_GRAM + NB_ROW + NB_R20) cnt += p[0];
      else { s10 += p[0]; s10l5 += p[1]; }
    }
    r0[t] = a; r1[t] = bc; r2[t] = cnt; r3[t] = s10; r4[t] = s10l5;
    __syncthreads();
    for (int sft = 128; sft; sft >>= 1) {
      if (t < sft) {
        r0[t] += r0[t + sft]; r1[t] += r1[t + sft]; r2[t] += r2[t + sft];
        r3[t] += r3[t + sft]; r4[t] += r4[t + sft];
      }
      __syncthreads();
    }
    if (t == 0) {
      wsd[2] = r0[0];   // sumstd
      wsd[3] = r1[0];   // conc
      wsd[4] = r2[0];   // cnt20
      wsd[5] = r3[0];   // sum10
      wsd[6] = r4[0];   // sum10l5
    }
  }
  // ---- MLP ----
  f[t] = (t < AN) ? x[(size_t)(TN - 1) * AN + t] : pos[t - AN];
  __syncthreads();
  {
    int n = t & 127, h = t >> 7;
    float acc = 0.f;
    const float* wcol = w1 + h * 128 * AN + n;
    const float* fv = f + h * 128;
    for (int k = 0; k < 128; ++k) acc = fmaf(fv[k], wcol[k * AN], acc);
    prt[t] = acc;
  }
  __syncthreads();
  if (t < AN) {
    float acc = b1[t] + prt[t] + prt[t + 128];
    acc = fmaxf(acc, 0.0f);
    h1[t] = gamma[t] * (acc / sqrtf(1.0f + 1e-5f)) + beta[t];
  }
  __syncthreads();
  if (t < 64) {
    float acc = b2[t];
    for (int k = 0; k < AN; ++k) acc = fmaf(h1[k], w2[k * 64 + t], acc);
    h2[t] = fmaxf(acc, 0.0f);
  }
  __syncthreads();
  if (t < 3) {
    float acc = b3[t];
    for (int k = 0; k < 64; ++k) acc = fmaf(h2[k], w3[k * 3 + t], acc);
    lg[t] = acc;
  }
  // ---- pos |.| sum/max, wave-parallel ----
  if (t < AN) {
    double pa = fabs((double)pos[t]);
    double ps = pa, pm = pa;
#pragma unroll
    for (int o = 32; o; o >>= 1) {
      ps += __shfl_xor(ps, o);
      pm = fmax(pm, __shfl_xor(pm, o));
    }
    if (lane == 0) { pr2[w] = ps; pr2[2 + w] = pm; }
  }
  __syncthreads();
  if (t == 0) {
    float m = fmaxf(lg[0], fmaxf(lg[1], lg[2]));
    float e0 = expf(lg[0] - m), e1 = expf(lg[1] - m), e2 = expf(lg[2] - m);
    wsd[WS_SEV] = (double)(e2 / (e0 + e1 + e2));
    wsd[WS_PAS] = pr2[0] + pr2[1];
    wsd[WS_PAM] = fmax(pr2[2], pr2[3]);
  }
}

// ====== phase C: spec fold + power iteration + assembly (single block) ===
__global__ void __launch_bounds__(256) k_spec_tail(
    const double* __restrict__ wsd, const float* __restrict__ corr,
    float* __restrict__ out) {
  __shared__ float vv[AN], prt[256], un[AN], red[4];
  __shared__ double spec[3];
  int t = threadIdx.x;
  int lane = t & 63;
  int w = t >> 6;
  if (t < 64) {                       // wave 0: fold spec partials
    double s0 = wsd[WS_SPEC + t * 3 + 0];
    double s1 = wsd[WS_SPEC + t * 3 + 1];
    double s2 = wsd[WS_SPEC + t * 3 + 2];
#pragma unroll
    for (int o = 32; o; o >>= 1) {
      s0 += __shfl_xor(s0, o);
      s1 += __shfl_xor(s1, o);
      s2 += __shfl_xor(s2, o);
    }
    if (t == 0) { spec[0] = s0; spec[1] = s1; spec[2] = s2; }
  }
  if (t < AN) vv[t] = 1.0f;
  __syncthreads();
  // ---- power iteration, 12 iters; transposed (symmetric) coalesced reads:
  // thread computes output col c from rows hh*64..hh*64+63; corr is bitwise
  // symmetric so this is exact. Lanes read consecutive addresses.
  int c = t & (AN - 1), hh = t >> 7;
  const float* cp = corr + (size_t)hh * 64 * AN + c;
  float lam = 0.0f;
  for (int it = 0; it < 12; ++it) {
    float acc = 0.f;
#pragma unroll
    for (int k = 0; k < 64; ++k)
      acc = fmaf(cp[(size_t)k * AN], vv[hh * 64 + k], acc);
    prt[t] = acc;
    __syncthreads();
    if (t < AN) {
      float u = prt[t] + prt[t + 128];
      un[t] = u;
      float sq = u * u;
#pragma unroll
      for (int o = 32; o; o >>= 1) sq += __shfl_xor(sq, o);
      if (lane == 0) red[w] = sq;
    }
    __syncthreads();
    lam = sqrtf(red[0] + red[1]);
    if (t < AN) vv[t] = un[t] / lam;
    __syncthreads();
  }
  // ---- final assembly ----
  if (t != 0) return;
  double sev = wsd[WS_SEV];
  double sumstd = wsd[2], conc = wsd[3], cnt20 = wsd[4];
  double sum10 = wsd[5], sum10l5 = wsd[6];
  double avg_disp = sumstd / (double)TN;
  double trend = -(wsd[WS_STDL] - wsd[WS_STD0]) / (double)(TN - 1);
  double hi = trend / (avg_disp + 1e-6) + 0.5;
  hi = fmin(1.0, fmax(0.0, hi));
  double avg_corr = (spec[0] - spec[2]) / ((double)AN * (AN - 1));
  double sync_ind = (double)lam / (double)AN;
  double sync_risk = fmin(1.0, sync_ind * avg_corr);
  double pl = cnt20 / (double)(TN - 20);
  double rd = 1.0 - spec[1] / ((double)AN * AN);
  double pd = 1.0 - wsd[WS_PAM] / wsd[WS_PAS];
  double dl = 1.0 - sqrt(rd * pd);
  double recent = sum10l5 / 5.0;
  double hist = (sum10 - sum10l5) / (double)(TN - 10 - 5);
  double sraw = (recent - hist) / hist;
  sraw = fmin(1.0, fmax(0.0, sraw));
  double surge = (hist > 0.0) ? sraw : 0.0;
  double ac = (conc / (double)TN - (double)AN) / ((double)AN * (AN - 1));
  double pcup = fmin(1.0, fmax(0.0, (ac - 0.5) * 2.0));
  double cr = (hi + sync_risk + dl) / 3.0;
  out[0] = (float)hi;
  out[1] = (float)sev;
  out[2] = (float)sync_risk;
  out[3] = (float)pl;
  out[4] = (float)dl;
  out[5] = (float)surge;
  out[6] = (float)pcup;
  out[7] = (float)cr;
}

extern "C" void kernel_launch(void* const* d_in, const int* in_sizes, int n_in,
                              void* d_out, int out_size, void* d_ws, size_t ws_size,
                              hipStream_t stream) {
  const float* x     = (const float*)d_in[0];
  const float* pos   = (const float*)d_in[1];
  const float* w1    = (const float*)d_in[2];
  const float* b1    = (const float*)d_in[3];
  const float* gamma = (const float*)d_in[4];
  const float* beta  = (const float*)d_in[5];
  const float* w2    = (const float*)d_in[6];
  const float* b2    = (const float*)d_in[7];
  const float* w3    = (const float*)d_in[8];
  const float* b3    = (const float*)d_in[9];
  float* out = (float*)d_out;
  double* wsd = (double*)d_ws;
  float* corr = (float*)(wsd + WS_DEND);               // [16384]
  float* pc   = corr + AN * AN;                        // [64*128]
  float* pdg  = pc + NB_GRAM * AN;                     // [64*128]
  float* pg   = pdg + NB_GRAM * AN;                    // [64*16384]

  k_main<<<NB_WORK, 256, 0, stream>>>(x, wsd, pc, pdg, pg);
  k_fold<<<65, 256, 0, stream>>>(pc, pdg, pg, wsd, corr, x, pos, w1, b1,
                                 gamma, beta, w2, b2, w3, b3);
  k_spec_tail<<<1, 256, 0, stream>>>(wsd, corr, out);
}

// Round 4
// 114.644 us; speedup vs baseline: 1.6005x; 1.1081x over previous
//
#include <hip/hip_runtime.h>
#include <math.h>

#define TN 8192
#define AN 128
#define NW20 (TN - 20)   // 8172
#define NW10 (TN - 10)   // 8182

// ---- k_main grid ranges ----
#define NB_GRAM 128      // 64 rows/slice (R4: revert to R0's gram split)
#define NB_ROW  512      // 16 rows/block
#define NB_R20  511      // 16 windows/block (4 waves x strip of 4)
#define NB_R10  512
#define NB_WORK (NB_GRAM + NB_ROW + NB_R20 + NB_R10)   // 1663

// ---- workspace double-layout ----
#define WS_STD0 0
#define WS_STDL 1
// wsd[2..6]: sumstd, conc, cnt20, sum10, sum10l5   (written by k_fold b==64)
#define WS_SEV  7                    // herding_severity (k_fold b==64)
#define WS_SPEC 8                    // 64*3 {sum, sumabs, trace}
#define WS_BLK  200                  // NB_WORK*2 per-block scalar slots (to 3526)
#define WS_PAS  3600                 // sum |pos|
#define WS_PAM  3601                 // max |pos|
#define WS_DEND 4096

// rolling off-diag corr via C.sum() = sum_t (sum_i z_ti)^2; butterfly with
// lane-compression; 4 consecutive windows per wave from one register strip.
// Math verified earlier (absmax 7.45e-9). Lane owns columns {2*lane, 2*lane+1}
// (column permutation is neutral: all reductions are symmetric over columns).
template <int W>
__device__ __forceinline__ void roll_strip4(const float* __restrict__ x,
                                            int s0, int nwin, int lane,
                                            double& accA, double& accB) {
  constexpr int NR = W + 3;
  float a0[NR], a1[NR];
#pragma unroll
  for (int t = 0; t < NR; ++t) {
    int r = s0 + t; r = (r < TN) ? r : (TN - 1);
    float2 v = *(const float2*)(x + (size_t)r * AN + 2 * lane);
    a0[t] = v.x; a1[t] = v.y;
  }
#pragma unroll
  for (int w4 = 0; w4 < 4; ++w4) {
    int s = s0 + w4;
    if (s < nwin) {
      float sf0 = 0.f, sf1 = 0.f;
#pragma unroll
      for (int t = 0; t < W; ++t) { sf0 += a0[w4 + t]; sf1 += a1[w4 + t]; }
      float mu0 = sf0 / W, mu1 = sf1 / W;
      float v0 = 0.f, v1 = 0.f;
#pragma unroll
      for (int t = 0; t < W; ++t) {
        float d0 = a0[w4 + t] - mu0, d1 = a1[w4 + t] - mu1;
        v0 += d0 * d0; v1 += d1 * d1;
      }
      float i0 = 1.0f / sqrtf(v0), i1 = 1.0f / sqrtf(v1);
      float q[W];
#pragma unroll
      for (int t = 0; t < W; ++t)
        q[t] = (a0[w4 + t] - mu0) * i0 + (a1[w4 + t] - mu1) * i1;
      int n = W;
#pragma unroll
      for (int o = 1; o <= 32; o <<= 1) {
#pragma unroll
        for (int k = 0; k < n; ++k) q[k] += __shfl_xor(q[k], o);
        if (n > 1) {
          int nh = n >> 1;
          bool hi = (lane & o) != 0;
#pragma unroll
          for (int k = 0; k < nh; ++k) q[k] = hi ? q[2 * k + 1] : q[2 * k];
          if (n & 1) { q[nh] = q[2 * nh]; n = nh + 1; } else { n = nh; }
        }
      }
      float alpha = (W == 20) ? ((lane & 16) ? 0.125f : 0.5f)
                              : ((lane & 8) ? 0.0625f : 0.25f);
      float r = q[0] * q[0] * alpha;
#pragma unroll
      for (int o = 32; o; o >>= 1) r += __shfl_xor(r, o);
      if (lane == 0) {
        double off = ((double)r - (double)AN) / ((double)AN * (AN - 1));
        if (W == 20) {
          accA += (off > 0.7) ? 1.0 : 0.0;
        } else {
          accA += off;
          if (s >= TN - W - 5) accB += off;
        }
      }
    }
  }
}

// ============ phase A: all data-parallel work, deterministic slots =======
__global__ void __launch_bounds__(256) k_main(const float* __restrict__ x,
                                              double* __restrict__ wsd,
                                              float* __restrict__ pc,
                                              float* __restrict__ pdg,
                                              float* __restrict__ pg) {
  __shared__ union {
    float stage[8][AN];
    double tacc[4][2];
  } sm;
  const int b = blockIdx.x;
  const int tid = threadIdx.x;
  const int lane = tid & 63;
  const int w = tid >> 6;

  if (b < NB_GRAM) {
    // ---- gram slice: 64 rows, 8x8 register tiles (R0-verified) ----
    int i0 = (tid >> 4) * 8;
    int j0 = (tid & 15) * 8;
    int lrow = tid >> 5;
    int lcol = (tid & 31) * 4;
    const float* xs = x + (size_t)b * 64 * AN;
    float acc[8][8];
#pragma unroll
    for (int a = 0; a < 8; ++a)
#pragma unroll
      for (int c = 0; c < 8; ++c) acc[a][c] = 0.f;
    float4 v = *(const float4*)(xs + lrow * AN + lcol);
    for (int it = 0; it < 8; ++it) {
      __syncthreads();
      *(float4*)(&sm.stage[lrow][lcol]) = v;
      __syncthreads();
      if (it + 1 < 8)
        v = *(const float4*)(xs + ((it + 1) * 8 + lrow) * AN + lcol);
#pragma unroll
      for (int r = 0; r < 8; ++r) {
        float aa[8], bb[8];
        *(float4*)(aa) = *(const float4*)(&sm.stage[r][i0]);
        *(float4*)(aa + 4) = *(const float4*)(&sm.stage[r][i0 + 4]);
        *(float4*)(bb) = *(const float4*)(&sm.stage[r][j0]);
        *(float4*)(bb + 4) = *(const float4*)(&sm.stage[r][j0 + 4]);
#pragma unroll
        for (int ai = 0; ai < 8; ++ai)
#pragma unroll
          for (int bj = 0; bj < 8; ++bj)
            acc[ai][bj] = fmaf(aa[ai], bb[bj], acc[ai][bj]);
      }
    }
    float* dst = pg + (size_t)b * (AN * AN);
#pragma unroll
    for (int ai = 0; ai < 8; ++ai)
#pragma unroll
      for (int bj = 0; bj < 8; bj += 4)
        *(float4*)(dst + (i0 + ai) * AN + j0 + bj) =
            make_float4(acc[ai][bj], acc[ai][bj + 1], acc[ai][bj + 2],
                        acc[ai][bj + 3]);
    if ((tid >> 4) == (tid & 15)) {
#pragma unroll
      for (int k = 0; k < 8; ++k) pdg[b * AN + i0 + k] = acc[k][k];
    }
    if (tid < AN) {
      float cs = 0.f;
      for (int r = 0; r < 64; ++r) cs += xs[r * AN + tid];
      pc[b * AN + tid] = cs;
    }
    return;
  }

  if (b < NB_GRAM + NB_ROW) {
    // ---- per-row std + sign counts, 16 rows/block, float2 cols ----
    int rb = b - NB_GRAM;
    double sstd = 0.0, sconc = 0.0;
    for (int rr = 0; rr < 4; ++rr) {
      int t = rb * 16 + w * 4 + rr;
      float2 xv = *(const float2*)(x + (size_t)t * AN + 2 * lane);
      float x0 = xv.x, x1 = xv.y;
      float s = x0 + x1;
#pragma unroll
      for (int o = 32; o; o >>= 1) s += __shfl_xor(s, o);
      float mean = s * (1.0f / AN);
      float d0 = x0 - mean, d1 = x1 - mean;
      float q = d0 * d0 + d1 * d1;
#pragma unroll
      for (int o = 32; o; o >>= 1) q += __shfl_xor(q, o);
      float sd = sqrtf(q / (float)(AN - 1));
      int pk = (int)(x0 < 0.f) + (int)(x1 < 0.f)
             + (((int)(x0 == 0.f) + (int)(x1 == 0.f)) << 10)
             + (((int)(x0 > 0.f) + (int)(x1 > 0.f)) << 20);
#pragma unroll
      for (int o = 32; o; o >>= 1) pk += __shfl_xor(pk, o);
      if (lane == 0) {
        int nn = pk & 1023, nz = (pk >> 10) & 1023, np = (pk >> 20) & 1023;
        sconc += (double)nn * nn + (double)nz * nz + (double)np * np;
        sstd += (double)sd;
        if (t == 0) wsd[WS_STD0] = (double)sd;
        if (t == TN - 1) wsd[WS_STDL] = (double)sd;
      }
    }
    if (lane == 0) { sm.tacc[w][0] = sstd; sm.tacc[w][1] = sconc; }
    __syncthreads();
    if (tid == 0) {
      wsd[WS_BLK + (size_t)b * 2 + 0] =
          sm.tacc[0][0] + sm.tacc[1][0] + sm.tacc[2][0] + sm.tacc[3][0];
      wsd[WS_BLK + (size_t)b * 2 + 1] =
          sm.tacc[0][1] + sm.tacc[1][1] + sm.tacc[2][1] + sm.tacc[3][1];
    }
    return;
  }

  if (b < NB_GRAM + NB_ROW + NB_R20) {
    int s0 = (b - (NB_GRAM + NB_ROW)) * 16 + w * 4;
    double cnt = 0.0, dummy = 0.0;
    roll_strip4<20>(x, s0, NW20, lane, cnt, dummy);
    if (lane == 0) { sm.tacc[w][0] = cnt; }
    __syncthreads();
    if (tid == 0)
      wsd[WS_BLK + (size_t)b * 2 + 0] =
          sm.tacc[0][0] + sm.tacc[1][0] + sm.tacc[2][0] + sm.tacc[3][0];
    return;
  }

  {
    int s0 = (b - (NB_GRAM + NB_ROW + NB_R20)) * 16 + w * 4;
    double s10 = 0.0, s10l5 = 0.0;
    roll_strip4<10>(x, s0, NW10, lane, s10, s10l5);
    if (lane == 0) { sm.tacc[w][0] = s10; sm.tacc[w][1] = s10l5; }
    __syncthreads();
    if (tid == 0) {
      wsd[WS_BLK + (size_t)b * 2 + 0] =
          sm.tacc[0][0] + sm.tacc[1][0] + sm.tacc[2][0] + sm.tacc[3][0];
      wsd[WS_BLK + (size_t)b * 2 + 1] =
          sm.tacc[0][1] + sm.tacc[1][1] + sm.tacc[2][1] + sm.tacc[3][1];
    }
  }
}

// ====== phase B: fold partials -> corr (b<64) + scalar folds/MLP/pos (b==64)
__global__ void __launch_bounds__(256) k_fold(
    const float* __restrict__ pc, const float* __restrict__ pdg,
    const float* __restrict__ pg, double* __restrict__ wsd,
    float* __restrict__ corr, const float* __restrict__ x,
    const float* __restrict__ pos, const float* __restrict__ w1,
    const float* __restrict__ b1, const float* __restrict__ gamma,
    const float* __restrict__ beta, const float* __restrict__ w2,
    const float* __restrict__ b2, const float* __restrict__ w3,
    const float* __restrict__ b3) {
  __shared__ double r0[256], r1[256], r2[256], r3[256], r4[256];
  int b = blockIdx.x;
  int t = threadIdx.x;
  int lane = t & 63;
  int w = t >> 6;
  if (b < 64) {
    // ---- mu/sigma pass split across all 256 threads (order-preserving) ----
    __shared__ double muS[AN], dS[AN], csP[AN], dgP[AN];
    if (t < AN) {
      double cs = 0.0;
#pragma unroll 16
      for (int s = 0; s < NB_GRAM; ++s) cs += (double)pc[s * AN + t];
      csP[t] = cs;
    } else {
      int u = t - AN;
      double dg = 0.0;
#pragma unroll 16
      for (int s = 0; s < NB_GRAM; ++s) dg += (double)pdg[s * AN + u];
      dgP[u] = dg;
    }
    __syncthreads();
    if (t < AN) {
      double mu = csP[t] / (double)TN;
      muS[t] = mu;
      dS[t] = sqrt(dgP[t] - (double)TN * mu * mu);
    }
    __syncthreads();
    int e = b * 256 + t;
    int i = e >> 7, j = e & (AN - 1);
    double cv = 0.0;
#pragma unroll 16
    for (int s = 0; s < NB_GRAM; ++s) cv += (double)pg[(size_t)s * (AN * AN) + e];
    cv -= (double)TN * muS[i] * muS[j];
    double c = cv / (dS[i] * dS[j]);
    corr[e] = (float)c;
    r0[t] = c;
    r1[t] = fabs(c);
    r2[t] = (i == j) ? c : 0.0;
    __syncthreads();
    for (int sft = 128; sft; sft >>= 1) {
      if (t < sft) { r0[t] += r0[t + sft]; r1[t] += r1[t + sft]; r2[t] += r2[t + sft]; }
      __syncthreads();
    }
    if (t == 0) {
      wsd[WS_SPEC + b * 3 + 0] = r0[0];
      wsd[WS_SPEC + b * 3 + 1] = r1[0];
      wsd[WS_SPEC + b * 3 + 2] = r2[0];
    }
    return;
  }

  // ---- block 64: scalar folds + MLP + pos scan (independent of corr) ----
  __shared__ float f[2 * AN], prt[256], h1[AN], h2[64], lg[3];
  __shared__ double pr2[4];
  {
    double a = 0.0, bc = 0.0, cnt = 0.0, s10 = 0.0, s10l5 = 0.0;
    for (int k = NB_GRAM + t; k < NB_WORK; k += 256) {
      const double* p = wsd + WS_BLK + (size_t)k * 2;
      if (k < NB_GRAM + NB_ROW) { a += p[0]; bc += p[1]; }
      else if (k < NB_GRAM + NB_ROW + NB_R20) cnt += p[0];
      else { s10 += p[0]; s10l5 += p[1]; }
    }
    r0[t] = a; r1[t] = bc; r2[t] = cnt; r3[t] = s10; r4[t] = s10l5;
    __syncthreads();
    for (int sft = 128; sft; sft >>= 1) {
      if (t < sft) {
        r0[t] += r0[t + sft]; r1[t] += r1[t + sft]; r2[t] += r2[t + sft];
        r3[t] += r3[t + sft]; r4[t] += r4[t + sft];
      }
      __syncthreads();
    }
    if (t == 0) {
      wsd[2] = r0[0];   // sumstd
      wsd[3] = r1[0];   // conc
      wsd[4] = r2[0];   // cnt20
      wsd[5] = r3[0];   // sum10
      wsd[6] = r4[0];   // sum10l5
    }
  }
  // ---- MLP ----
  f[t] = (t < AN) ? x[(size_t)(TN - 1) * AN + t] : pos[t - AN];
  __syncthreads();
  {
    int n = t & 127, h = t >> 7;
    float acc = 0.f;
    const float* wcol = w1 + h * 128 * AN + n;
    const float* fv = f + h * 128;
    for (int k = 0; k < 128; ++k) acc = fmaf(fv[k], wcol[k * AN], acc);
    prt[t] = acc;
  }
  __syncthreads();
  if (t < AN) {
    float acc = b1[t] + prt[t] + prt[t + 128];
    acc = fmaxf(acc, 0.0f);
    h1[t] = gamma[t] * (acc / sqrtf(1.0f + 1e-5f)) + beta[t];
  }
  __syncthreads();
  if (t < 64) {
    float acc = b2[t];
    for (int k = 0; k < AN; ++k) acc = fmaf(h1[k], w2[k * 64 + t], acc);
    h2[t] = fmaxf(acc, 0.0f);
  }
  __syncthreads();
  if (t < 3) {
    float acc = b3[t];
    for (int k = 0; k < 64; ++k) acc = fmaf(h2[k], w3[k * 3 + t], acc);
    lg[t] = acc;
  }
  // ---- pos |.| sum/max, wave-parallel ----
  if (t < AN) {
    double pa = fabs((double)pos[t]);
    double ps = pa, pm = pa;
#pragma unroll
    for (int o = 32; o; o >>= 1) {
      ps += __shfl_xor(ps, o);
      pm = fmax(pm, __shfl_xor(pm, o));
    }
    if (lane == 0) { pr2[w] = ps; pr2[2 + w] = pm; }
  }
  __syncthreads();
  if (t == 0) {
    float m = fmaxf(lg[0], fmaxf(lg[1], lg[2]));
    float e0 = expf(lg[0] - m), e1 = expf(lg[1] - m), e2 = expf(lg[2] - m);
    wsd[WS_SEV] = (double)(e2 / (e0 + e1 + e2));
    wsd[WS_PAS] = pr2[0] + pr2[1];
    wsd[WS_PAM] = fmax(pr2[2], pr2[3]);
  }
}

// ====== phase C: spec fold + power iteration + assembly (single block) ===
__global__ void __launch_bounds__(256) k_spec_tail(
    const double* __restrict__ wsd, const float* __restrict__ corr,
    float* __restrict__ out) {
  __shared__ float vv[AN], prt[256], un[AN], red[4];
  __shared__ double spec[3];
  int t = threadIdx.x;
  int lane = t & 63;
  int w = t >> 6;
  // ---- register-cache this thread's corr column strip; issue loads NOW so
  // they overlap the spec fold below. Same values/order as the R3 loop ->
  // bit-identical power iteration.
  int c = t & (AN - 1), hh = t >> 7;
  const float* cp = corr + (size_t)hh * 64 * AN + c;
  float creg[64];
#pragma unroll
  for (int k = 0; k < 64; ++k) creg[k] = cp[(size_t)k * AN];
  if (t < 64) {                       // wave 0: fold spec partials
    double s0 = wsd[WS_SPEC + t * 3 + 0];
    double s1 = wsd[WS_SPEC + t * 3 + 1];
    double s2 = wsd[WS_SPEC + t * 3 + 2];
#pragma unroll
    for (int o = 32; o; o >>= 1) {
      s0 += __shfl_xor(s0, o);
      s1 += __shfl_xor(s1, o);
      s2 += __shfl_xor(s2, o);
    }
    if (t == 0) { spec[0] = s0; spec[1] = s1; spec[2] = s2; }
  }
  if (t < AN) vv[t] = 1.0f;
  __syncthreads();
  // ---- power iteration, 12 iters, corr in registers ----
  float lam = 0.0f;
  for (int it = 0; it < 12; ++it) {
    float acc = 0.f;
#pragma unroll
    for (int k = 0; k < 64; ++k)
      acc = fmaf(creg[k], vv[hh * 64 + k], acc);
    prt[t] = acc;
    __syncthreads();
    if (t < AN) {
      float u = prt[t] + prt[t + 128];
      un[t] = u;
      float sq = u * u;
#pragma unroll
      for (int o = 32; o; o >>= 1) sq += __shfl_xor(sq, o);
      if (lane == 0) red[w] = sq;
    }
    __syncthreads();
    lam = sqrtf(red[0] + red[1]);
    if (t < AN) vv[t] = un[t] / lam;
    __syncthreads();
  }
  // ---- final assembly ----
  if (t != 0) return;
  double sev = wsd[WS_SEV];
  double sumstd = wsd[2], conc = wsd[3], cnt20 = wsd[4];
  double sum10 = wsd[5], sum10l5 = wsd[6];
  double avg_disp = sumstd / (double)TN;
  double trend = -(wsd[WS_STDL] - wsd[WS_STD0]) / (double)(TN - 1);
  double hi = trend / (avg_disp + 1e-6) + 0.5;
  hi = fmin(1.0, fmax(0.0, hi));
  double avg_corr = (spec[0] - spec[2]) / ((double)AN * (AN - 1));
  double sync_ind = (double)lam / (double)AN;
  double sync_risk = fmin(1.0, sync_ind * avg_corr);
  double pl = cnt20 / (double)(TN - 20);
  double rd = 1.0 - spec[1] / ((double)AN * AN);
  double pd = 1.0 - wsd[WS_PAM] / wsd[WS_PAS];
  double dl = 1.0 - sqrt(rd * pd);
  double recent = sum10l5 / 5.0;
  double hist = (sum10 - sum10l5) / (double)(TN - 10 - 5);
  double sraw = (recent - hist) / hist;
  sraw = fmin(1.0, fmax(0.0, sraw));
  double surge = (hist > 0.0) ? sraw : 0.0;
  double ac = (conc / (double)TN - (double)AN) / ((double)AN * (AN - 1));
  double pcup = fmin(1.0, fmax(0.0, (ac - 0.5) * 2.0));
  double cr = (hi + sync_risk + dl) / 3.0;
  out[0] = (float)hi;
  out[1] = (float)sev;
  out[2] = (float)sync_risk;
  out[3] = (float)pl;
  out[4] = (float)dl;
  out[5] = (float)surge;
  out[6] = (float)pcup;
  out[7] = (float)cr;
}

extern "C" void kernel_launch(void* const* d_in, const int* in_sizes, int n_in,
                              void* d_out, int out_size, void* d_ws, size_t ws_size,
                              hipStream_t stream) {
  const float* x     = (const float*)d_in[0];
  const float* pos   = (const float*)d_in[1];
  const float* w1    = (const float*)d_in[2];
  const float* b1    = (const float*)d_in[3];
  const float* gamma = (const float*)d_in[4];
  const float* beta  = (const float*)d_in[5];
  const float* w2    = (const float*)d_in[6];
  const float* b2    = (const float*)d_in[7];
  const float* w3    = (const float*)d_in[8];
  const float* b3    = (const float*)d_in[9];
  float* out = (float*)d_out;
  double* wsd = (double*)d_ws;
  float* corr = (float*)(wsd + WS_DEND);               // [16384]
  float* pc   = corr + AN * AN;                        // [128*128]
  float* pdg  = pc + NB_GRAM * AN;                     // [128*128]
  float* pg   = pdg + NB_GRAM * AN;                    // [128*16384]

  k_main<<<NB_WORK, 256, 0, stream>>>(x, wsd, pc, pdg, pg);
  k_fold<<<65, 256, 0, stream>>>(pc, pdg, pg, wsd, corr, x, pos, w1, b1,
                                 gamma, beta, w2, b2, w3, b3);
  k_spec_tail<<<1, 256, 0, stream>>>(wsd, corr, out);
}

// Round 5
// 114.437 us; speedup vs baseline: 1.6034x; 1.0018x over previous
//
#include <hip/hip_runtime.h>
#include <math.h>

#define TN 8192
#define AN 128
#define NW20 (TN - 20)   // 8172
#define NW10 (TN - 10)   // 8182

// ---- k_main grid ranges (R5: row-stats fused into rolling-20 blocks) ----
#define NB_GRAM 128      // 64 rows/slice
#define NB_R20  512      // 16 windows + 16 row-stats per block
#define NB_R10  512
#define NB_WORK (NB_GRAM + NB_R20 + NB_R10)   // 1152

// ---- workspace double-layout ----
#define WS_STD0 0
#define WS_STDL 1
// wsd[2..6]: sumstd, conc, cnt20, sum10, sum10l5   (k_fold block 128)
#define WS_SEV  7                    // herding_severity
#define WS_SPEC 8                    // 128*3 {sum, sumabs, trace} -> 8..392
#define WS_PAS  396                  // sum |pos|
#define WS_PAM  397                  // max |pos|
#define WS_BLK  400                  // 4 slots/block, to 400+1152*4=5008
#define WS_DEND 8192

// rolling W=10 off-diag corr via C.sum() = sum_t (sum_i z_ti)^2 (R4-verified)
template <int W>
__device__ __forceinline__ void roll_strip4(const float* __restrict__ x,
                                            int s0, int nwin, int lane,
                                            double& accA, double& accB) {
  constexpr int NR = W + 3;
  float a0[NR], a1[NR];
#pragma unroll
  for (int t = 0; t < NR; ++t) {
    int r = s0 + t; r = (r < TN) ? r : (TN - 1);
    float2 v = *(const float2*)(x + (size_t)r * AN + 2 * lane);
    a0[t] = v.x; a1[t] = v.y;
  }
#pragma unroll
  for (int w4 = 0; w4 < 4; ++w4) {
    int s = s0 + w4;
    if (s < nwin) {
      float sf0 = 0.f, sf1 = 0.f;
#pragma unroll
      for (int t = 0; t < W; ++t) { sf0 += a0[w4 + t]; sf1 += a1[w4 + t]; }
      float mu0 = sf0 / W, mu1 = sf1 / W;
      float v0 = 0.f, v1 = 0.f;
#pragma unroll
      for (int t = 0; t < W; ++t) {
        float d0 = a0[w4 + t] - mu0, d1 = a1[w4 + t] - mu1;
        v0 += d0 * d0; v1 += d1 * d1;
      }
      float i0 = 1.0f / sqrtf(v0), i1 = 1.0f / sqrtf(v1);
      float q[W];
#pragma unroll
      for (int t = 0; t < W; ++t)
        q[t] = (a0[w4 + t] - mu0) * i0 + (a1[w4 + t] - mu1) * i1;
      int n = W;
#pragma unroll
      for (int o = 1; o <= 32; o <<= 1) {
#pragma unroll
        for (int k = 0; k < n; ++k) q[k] += __shfl_xor(q[k], o);
        if (n > 1) {
          int nh = n >> 1;
          bool hi = (lane & o) != 0;
#pragma unroll
          for (int k = 0; k < nh; ++k) q[k] = hi ? q[2 * k + 1] : q[2 * k];
          if (n & 1) { q[nh] = q[2 * nh]; n = nh + 1; } else { n = nh; }
        }
      }
      float alpha = (W == 20) ? ((lane & 16) ? 0.125f : 0.5f)
                              : ((lane & 8) ? 0.0625f : 0.25f);
      float r = q[0] * q[0] * alpha;
#pragma unroll
      for (int o = 32; o; o >>= 1) r += __shfl_xor(r, o);
      if (lane == 0) {
        double off = ((double)r - (double)AN) / ((double)AN * (AN - 1));
        if (W == 20) {
          accA += (off > 0.7) ? 1.0 : 0.0;
        } else {
          accA += off;
          if (s >= TN - W - 5) accB += off;
        }
      }
    }
  }
}

// W=20 strip with fused per-row stats for the strip's first 4 rows.
// Stats op-sequence copied verbatim from the old row-stats branch -> the
// per-row sd / sign-count values are bit-identical (same loads, same order).
__device__ __forceinline__ void roll20_stats(const float* __restrict__ x,
                                             int s0, int lane,
                                             double* __restrict__ wsd,
                                             double& cnt, double& sstd,
                                             double& sconc) {
  constexpr int W = 20, NR = 23;
  float a0[NR], a1[NR];
#pragma unroll
  for (int t = 0; t < NR; ++t) {
    int r = s0 + t; r = (r < TN) ? r : (TN - 1);
    float2 v = *(const float2*)(x + (size_t)r * AN + 2 * lane);
    a0[t] = v.x; a1[t] = v.y;
  }
  // ---- per-row stats: rows s0..s0+3 (all < TN by construction) ----
#pragma unroll
  for (int rr = 0; rr < 4; ++rr) {
    int t = s0 + rr;
    float x0 = a0[rr], x1 = a1[rr];
    float s = x0 + x1;
#pragma unroll
    for (int o = 32; o; o >>= 1) s += __shfl_xor(s, o);
    float mean = s * (1.0f / AN);
    float d0 = x0 - mean, d1 = x1 - mean;
    float q = d0 * d0 + d1 * d1;
#pragma unroll
    for (int o = 32; o; o >>= 1) q += __shfl_xor(q, o);
    float sd = sqrtf(q / (float)(AN - 1));
    int pk = (int)(x0 < 0.f) + (int)(x1 < 0.f)
           + (((int)(x0 == 0.f) + (int)(x1 == 0.f)) << 10)
           + (((int)(x0 > 0.f) + (int)(x1 > 0.f)) << 20);
#pragma unroll
    for (int o = 32; o; o >>= 1) pk += __shfl_xor(pk, o);
    if (lane == 0) {
      int nn = pk & 1023, nz = (pk >> 10) & 1023, np = (pk >> 20) & 1023;
      sconc += (double)nn * nn + (double)nz * nz + (double)np * np;
      sstd += (double)sd;
      if (t == 0) wsd[WS_STD0] = (double)sd;
      if (t == TN - 1) wsd[WS_STDL] = (double)sd;
    }
  }
  // ---- rolling windows (identical to roll_strip4<20>) ----
#pragma unroll
  for (int w4 = 0; w4 < 4; ++w4) {
    int s = s0 + w4;
    if (s < NW20) {
      float sf0 = 0.f, sf1 = 0.f;
#pragma unroll
      for (int t = 0; t < W; ++t) { sf0 += a0[w4 + t]; sf1 += a1[w4 + t]; }
      float mu0 = sf0 / W, mu1 = sf1 / W;
      float v0 = 0.f, v1 = 0.f;
#pragma unroll
      for (int t = 0; t < W; ++t) {
        float d0 = a0[w4 + t] - mu0, d1 = a1[w4 + t] - mu1;
        v0 += d0 * d0; v1 += d1 * d1;
      }
      float i0 = 1.0f / sqrtf(v0), i1 = 1.0f / sqrtf(v1);
      float q[W];
#pragma unroll
      for (int t = 0; t < W; ++t)
        q[t] = (a0[w4 + t] - mu0) * i0 + (a1[w4 + t] - mu1) * i1;
      int n = W;
#pragma unroll
      for (int o = 1; o <= 32; o <<= 1) {
#pragma unroll
        for (int k = 0; k < n; ++k) q[k] += __shfl_xor(q[k], o);
        if (n > 1) {
          int nh = n >> 1;
          bool hi = (lane & o) != 0;
#pragma unroll
          for (int k = 0; k < nh; ++k) q[k] = hi ? q[2 * k + 1] : q[2 * k];
          if (n & 1) { q[nh] = q[2 * nh]; n = nh + 1; } else { n = nh; }
        }
      }
      float alpha = (lane & 16) ? 0.125f : 0.5f;
      float r = q[0] * q[0] * alpha;
#pragma unroll
      for (int o = 32; o; o >>= 1) r += __shfl_xor(r, o);
      if (lane == 0) {
        double off = ((double)r - (double)AN) / ((double)AN * (AN - 1));
        cnt += (off > 0.7) ? 1.0 : 0.0;
      }
    }
  }
}

// ============ phase A: all data-parallel work, deterministic slots =======
__global__ void __launch_bounds__(256) k_main(const float* __restrict__ x,
                                              double* __restrict__ wsd,
                                              float* __restrict__ pc,
                                              float* __restrict__ pdg,
                                              float* __restrict__ pg) {
  __shared__ union {
    float stage[8][AN];
    double tacc[4][3];
  } sm;
  const int b = blockIdx.x;
  const int tid = threadIdx.x;
  const int lane = tid & 63;
  const int w = tid >> 6;

  if (b < NB_GRAM) {
    // ---- gram slice: 64 rows, 8x8 register tiles (R0-verified) ----
    int i0 = (tid >> 4) * 8;
    int j0 = (tid & 15) * 8;
    int lrow = tid >> 5;
    int lcol = (tid & 31) * 4;
    const float* xs = x + (size_t)b * 64 * AN;
    float acc[8][8];
#pragma unroll
    for (int a = 0; a < 8; ++a)
#pragma unroll
      for (int c = 0; c < 8; ++c) acc[a][c] = 0.f;
    float4 v = *(const float4*)(xs + lrow * AN + lcol);
    for (int it = 0; it < 8; ++it) {
      __syncthreads();
      *(float4*)(&sm.stage[lrow][lcol]) = v;
      __syncthreads();
      if (it + 1 < 8)
        v = *(const float4*)(xs + ((it + 1) * 8 + lrow) * AN + lcol);
#pragma unroll
      for (int r = 0; r < 8; ++r) {
        float aa[8], bb[8];
        *(float4*)(aa) = *(const float4*)(&sm.stage[r][i0]);
        *(float4*)(aa + 4) = *(const float4*)(&sm.stage[r][i0 + 4]);
        *(float4*)(bb) = *(const float4*)(&sm.stage[r][j0]);
        *(float4*)(bb + 4) = *(const float4*)(&sm.stage[r][j0 + 4]);
#pragma unroll
        for (int ai = 0; ai < 8; ++ai)
#pragma unroll
          for (int bj = 0; bj < 8; ++bj)
            acc[ai][bj] = fmaf(aa[ai], bb[bj], acc[ai][bj]);
      }
    }
    float* dst = pg + (size_t)b * (AN * AN);
#pragma unroll
    for (int ai = 0; ai < 8; ++ai)
#pragma unroll
      for (int bj = 0; bj < 8; bj += 4)
        *(float4*)(dst + (i0 + ai) * AN + j0 + bj) =
            make_float4(acc[ai][bj], acc[ai][bj + 1], acc[ai][bj + 2],
                        acc[ai][bj + 3]);
    if ((tid >> 4) == (tid & 15)) {
#pragma unroll
      for (int k = 0; k < 8; ++k) pdg[b * AN + i0 + k] = acc[k][k];
    }
    if (tid < AN) {
      float cs = 0.f;
      for (int r = 0; r < 64; ++r) cs += xs[r * AN + tid];
      pc[b * AN + tid] = cs;
    }
    return;
  }

  if (b < NB_GRAM + NB_R20) {
    // ---- rolling-20 + fused row stats, 16 windows + 16 rows per block ----
    int s0 = (b - NB_GRAM) * 16 + w * 4;
    double cnt = 0.0, sstd = 0.0, sconc = 0.0;
    roll20_stats(x, s0, lane, wsd, cnt, sstd, sconc);
    if (lane == 0) {
      sm.tacc[w][0] = cnt; sm.tacc[w][1] = sstd; sm.tacc[w][2] = sconc;
    }
    __syncthreads();
    if (tid == 0) {
      wsd[WS_BLK + (size_t)b * 4 + 0] =
          sm.tacc[0][0] + sm.tacc[1][0] + sm.tacc[2][0] + sm.tacc[3][0];
      wsd[WS_BLK + (size_t)b * 4 + 1] =
          sm.tacc[0][1] + sm.tacc[1][1] + sm.tacc[2][1] + sm.tacc[3][1];
      wsd[WS_BLK + (size_t)b * 4 + 2] =
          sm.tacc[0][2] + sm.tacc[1][2] + sm.tacc[2][2] + sm.tacc[3][2];
    }
    return;
  }

  {
    int s0 = (b - (NB_GRAM + NB_R20)) * 16 + w * 4;
    double s10 = 0.0, s10l5 = 0.0;
    roll_strip4<10>(x, s0, NW10, lane, s10, s10l5);
    if (lane == 0) { sm.tacc[w][0] = s10; sm.tacc[w][1] = s10l5; }
    __syncthreads();
    if (tid == 0) {
      wsd[WS_BLK + (size_t)b * 4 + 0] =
          sm.tacc[0][0] + sm.tacc[1][0] + sm.tacc[2][0] + sm.tacc[3][0];
      wsd[WS_BLK + (size_t)b * 4 + 1] =
          sm.tacc[0][1] + sm.tacc[1][1] + sm.tacc[2][1] + sm.tacc[3][1];
    }
  }
}

// ====== phase B: corr fold (b<128, one row each) + scalar/MLP (b==128) ===
__global__ void __launch_bounds__(256) k_fold(
    const float* __restrict__ pc, const float* __restrict__ pdg,
    const float* __restrict__ pg, double* __restrict__ wsd,
    float* __restrict__ corr, const float* __restrict__ x,
    const float* __restrict__ pos, const float* __restrict__ w1,
    const float* __restrict__ b1, const float* __restrict__ gamma,
    const float* __restrict__ beta, const float* __restrict__ w2,
    const float* __restrict__ b2, const float* __restrict__ w3,
    const float* __restrict__ b3) {
  __shared__ double r0[256], r1[256], r2[256], r3[256], r4[256];
  int b = blockIdx.x;
  int t = threadIdx.x;
  int lane = t & 63;
  int w = t >> 6;
  if (b < 128) {
    // ---- corr row b: 2 threads/element, 64 slices each; mu/sd in-block ----
    __shared__ double muS[AN], dS[AN], csP[AN], dgP[AN], part[256];
    int j = t & 127, half = t >> 7;
    double cvp = 0.0;
    const float* pgp = pg + (size_t)(half * 64) * (AN * AN) + b * AN + j;
#pragma unroll 16
    for (int s = 0; s < 64; ++s) cvp += (double)pgp[(size_t)s * (AN * AN)];
    if (t < AN) {
      double cs = 0.0;
#pragma unroll 16
      for (int s = 0; s < NB_GRAM; ++s) cs += (double)pc[s * AN + t];
      csP[t] = cs;
    } else {
      int u = t - AN;
      double dg = 0.0;
#pragma unroll 16
      for (int s = 0; s < NB_GRAM; ++s) dg += (double)pdg[s * AN + u];
      dgP[u] = dg;
    }
    part[t] = cvp;
    __syncthreads();
    if (t < AN) {
      double mu = csP[t] / (double)TN;
      muS[t] = mu;
      dS[t] = sqrt(dgP[t] - (double)TN * mu * mu);
    }
    __syncthreads();
    if (t < 128) {
      double cv = part[t] + part[t + 128];
      cv -= (double)TN * muS[b] * muS[t];
      double c = cv / (dS[b] * dS[t]);
      corr[b * AN + t] = (float)c;
      r0[t] = c;
      r1[t] = fabs(c);
      r2[t] = (t == b) ? c : 0.0;
    } else {
      r0[t] = 0.0; r1[t] = 0.0; r2[t] = 0.0;
    }
    __syncthreads();
    for (int sft = 128; sft; sft >>= 1) {
      if (t < sft) { r0[t] += r0[t + sft]; r1[t] += r1[t + sft]; r2[t] += r2[t + sft]; }
      __syncthreads();
    }
    if (t == 0) {
      wsd[WS_SPEC + b * 3 + 0] = r0[0];
      wsd[WS_SPEC + b * 3 + 1] = r1[0];
      wsd[WS_SPEC + b * 3 + 2] = r2[0];
    }
    return;
  }

  // ---- block 128: scalar folds + MLP + pos scan (independent of corr) ----
  __shared__ float f[2 * AN], prt[256], h1[AN], h2[64], lg[3];
  __shared__ double pr2[4];
  {
    double cnt = 0.0, sstd = 0.0, sconc = 0.0, s10 = 0.0, s10l5 = 0.0;
    for (int k = NB_GRAM + t; k < NB_WORK; k += 256) {
      const double* p = wsd + WS_BLK + (size_t)k * 4;
      if (k < NB_GRAM + NB_R20) { cnt += p[0]; sstd += p[1]; sconc += p[2]; }
      else { s10 += p[0]; s10l5 += p[1]; }
    }
    r0[t] = sstd; r1[t] = sconc; r2[t] = cnt; r3[t] = s10; r4[t] = s10l5;
    __syncthreads();
    for (int sft = 128; sft; sft >>= 1) {
      if (t < sft) {
        r0[t] += r0[t + sft]; r1[t] += r1[t + sft]; r2[t] += r2[t + sft];
        r3[t] += r3[t + sft]; r4[t] += r4[t + sft];
      }
      __syncthreads();
    }
    if (t == 0) {
      wsd[2] = r0[0];   // sumstd
      wsd[3] = r1[0];   // conc
      wsd[4] = r2[0];   // cnt20
      wsd[5] = r3[0];   // sum10
      wsd[6] = r4[0];   // sum10l5
    }
  }
  // ---- MLP ----
  f[t] = (t < AN) ? x[(size_t)(TN - 1) * AN + t] : pos[t - AN];
  __syncthreads();
  {
    int n = t & 127, h = t >> 7;
    float acc = 0.f;
    const float* wcol = w1 + h * 128 * AN + n;
    const float* fv = f + h * 128;
    for (int k = 0; k < 128; ++k) acc = fmaf(fv[k], wcol[k * AN], acc);
    prt[t] = acc;
  }
  __syncthreads();
  if (t < AN) {
    float acc = b1[t] + prt[t] + prt[t + 128];
    acc = fmaxf(acc, 0.0f);
    h1[t] = gamma[t] * (acc / sqrtf(1.0f + 1e-5f)) + beta[t];
  }
  __syncthreads();
  if (t < 64) {
    float acc = b2[t];
    for (int k = 0; k < AN; ++k) acc = fmaf(h1[k], w2[k * 64 + t], acc);
    h2[t] = fmaxf(acc, 0.0f);
  }
  __syncthreads();
  if (t < 3) {
    float acc = b3[t];
    for (int k = 0; k < 64; ++k) acc = fmaf(h2[k], w3[k * 3 + t], acc);
    lg[t] = acc;
  }
  // ---- pos |.| sum/max, wave-parallel ----
  if (t < AN) {
    double pa = fabs((double)pos[t]);
    double ps = pa, pm = pa;
#pragma unroll
    for (int o = 32; o; o >>= 1) {
      ps += __shfl_xor(ps, o);
      pm = fmax(pm, __shfl_xor(pm, o));
    }
    if (lane == 0) { pr2[w] = ps; pr2[2 + w] = pm; }
  }
  __syncthreads();
  if (t == 0) {
    float m = fmaxf(lg[0], fmaxf(lg[1], lg[2]));
    float e0 = expf(lg[0] - m), e1 = expf(lg[1] - m), e2 = expf(lg[2] - m);
    wsd[WS_SEV] = (double)(e2 / (e0 + e1 + e2));
    wsd[WS_PAS] = pr2[0] + pr2[1];
    wsd[WS_PAM] = fmax(pr2[2], pr2[3]);
  }
}

// ====== phase C: spec fold + power iteration + assembly (single block) ===
__global__ void __launch_bounds__(256) k_spec_tail(
    const double* __restrict__ wsd, const float* __restrict__ corr,
    float* __restrict__ out) {
  __shared__ float vv[AN], prt[256], un[AN], red[4];
  __shared__ double specW[2][3];
  int t = threadIdx.x;
  int lane = t & 63;
  int w = t >> 6;
  // ---- register-cache this thread's corr column strip (R4-verified) ----
  int c = t & (AN - 1), hh = t >> 7;
  const float* cp = corr + (size_t)hh * 64 * AN + c;
  float creg[64];
#pragma unroll
  for (int k = 0; k < 64; ++k) creg[k] = cp[(size_t)k * AN];
  if (t < 128) {                      // waves 0-1: fold 128 spec partials
    double s0 = wsd[WS_SPEC + t * 3 + 0];
    double s1 = wsd[WS_SPEC + t * 3 + 1];
    double s2 = wsd[WS_SPEC + t * 3 + 2];
#pragma unroll
    for (int o = 32; o; o >>= 1) {
      s0 += __shfl_xor(s0, o);
      s1 += __shfl_xor(s1, o);
      s2 += __shfl_xor(s2, o);
    }
    if (lane == 0) { specW[w][0] = s0; specW[w][1] = s1; specW[w][2] = s2; }
  }
  if (t < AN) vv[t] = 1.0f;
  __syncthreads();
  // ---- power iteration, 12 iters, corr in registers ----
  float lam = 0.0f;
  for (int it = 0; it < 12; ++it) {
    float acc = 0.f;
#pragma unroll
    for (int k = 0; k < 64; ++k)
      acc = fmaf(creg[k], vv[hh * 64 + k], acc);
    prt[t] = acc;
    __syncthreads();
    if (t < AN) {
      float u = prt[t] + prt[t + 128];
      un[t] = u;
      float sq = u * u;
#pragma unroll
      for (int o = 32; o; o >>= 1) sq += __shfl_xor(sq, o);
      if (lane == 0) red[w] = sq;
    }
    __syncthreads();
    lam = sqrtf(red[0] + red[1]);
    if (t < AN) vv[t] = un[t] / lam;
    __syncthreads();
  }
  // ---- final assembly ----
  if (t != 0) return;
  double spec0 = specW[0][0] + specW[1][0];
  double spec1 = specW[0][1] + specW[1][1];
  double spec2 = specW[0][2] + specW[1][2];
  double sev = wsd[WS_SEV];
  double sumstd = wsd[2], conc = wsd[3], cnt20 = wsd[4];
  double sum10 = wsd[5], sum10l5 = wsd[6];
  double avg_disp = sumstd / (double)TN;
  double trend = -(wsd[WS_STDL] - wsd[WS_STD0]) / (double)(TN - 1);
  double hi = trend / (avg_disp + 1e-6) + 0.5;
  hi = fmin(1.0, fmax(0.0, hi));
  double avg_corr = (spec0 - spec2) / ((double)AN * (AN - 1));
  double sync_ind = (double)lam / (double)AN;
  double sync_risk = fmin(1.0, sync_ind * avg_corr);
  double pl = cnt20 / (double)(TN - 20);
  double rd = 1.0 - spec1 / ((double)AN * AN);
  double pd = 1.0 - wsd[WS_PAM] / wsd[WS_PAS];
  double dl = 1.0 - sqrt(rd * pd);
  double recent = sum10l5 / 5.0;
  double hist = (sum10 - sum10l5) / (double)(TN - 10 - 5);
  double sraw = (recent - hist) / hist;
  sraw = fmin(1.0, fmax(0.0, sraw));
  double surge = (hist > 0.0) ? sraw : 0.0;
  double ac = (conc / (double)TN - (double)AN) / ((double)AN * (AN - 1));
  double pcup = fmin(1.0, fmax(0.0, (ac - 0.5) * 2.0));
  double cr = (hi + sync_risk + dl) / 3.0;
  out[0] = (float)hi;
  out[1] = (float)sev;
  out[2] = (float)sync_risk;
  out[3] = (float)pl;
  out[4] = (float)dl;
  out[5] = (float)surge;
  out[6] = (float)pcup;
  out[7] = (float)cr;
}

extern "C" void kernel_launch(void* const* d_in, const int* in_sizes, int n_in,
                              void* d_out, int out_size, void* d_ws, size_t ws_size,
                              hipStream_t stream) {
  const float* x     = (const float*)d_in[0];
  const float* pos   = (const float*)d_in[1];
  const float* w1    = (const float*)d_in[2];
  const float* b1    = (const float*)d_in[3];
  const float* gamma = (const float*)d_in[4];
  const float* beta  = (const float*)d_in[5];
  const float* w2    = (const float*)d_in[6];
  const float* b2    = (const float*)d_in[7];
  const float* w3    = (const float*)d_in[8];
  const float* b3    = (const float*)d_in[9];
  float* out = (float*)d_out;
  double* wsd = (double*)d_ws;
  float* corr = (float*)(wsd + WS_DEND);               // [16384]
  float* pc   = corr + AN * AN;                        // [128*128]
  float* pdg  = pc + NB_GRAM * AN;                     // [128*128]
  float* pg   = pdg + NB_GRAM * AN;                    // [128*16384]

  k_main<<<NB_WORK, 256, 0, stream>>>(x, wsd, pc, pdg, pg);
  k_fold<<<129, 256, 0, stream>>>(pc, pdg, pg, wsd, corr, x, pos, w1, b1,
                                  gamma, beta, w2, b2, w3, b3);
  k_spec_tail<<<1, 256, 0, stream>>>(wsd, corr, out);
}